// Round 3
// baseline (478.022 us; speedup 1.0000x reference)
//
#include <hip/hip_runtime.h>

// Problem constants
#define B_    64
#define C_    3
#define H_    384
#define W_    384
#define P_    16
#define E_    768
#define N_    576                 // patches per image
#define M_    (B_ * N_)           // 36864 total patches
#define K_    (C_ * P_ * P_)      // 768 reduction dim
#define HW_   (H_ * W_)
#define CHW_  (C_ * H_ * W_)

// GEMM tiling
#define BM    128
#define BN    128
#define BK    64
#define KITERS (K_ / BK)          // 12

typedef __attribute__((ext_vector_type(8))) short  short8;   // bf16x8 MFMA operand
typedef __attribute__((ext_vector_type(4))) float  f32x4;    // MFMA accumulator

// round-to-nearest-even f32 pair -> packed bf16x2 (low = a). Bit-identical to
// the original gather's f2bf.
__device__ __forceinline__ unsigned int rnepair(float a, float b) {
    unsigned ua = __float_as_uint(a), ub = __float_as_uint(b);
    ua += 0x7FFFu + ((ua >> 16) & 1u);
    ub += 0x7FFFu + ((ub >> 16) & 1u);
    return (ua >> 16) | (ub & 0xFFFF0000u);
}

// 16B load with only 4B alignment guaranteed (xs is arbitrary).
__device__ __forceinline__ float4 ld16u(const float* p) {
    float4 v;
    __builtin_memcpy(&v, p, 16);
    return v;
}

// Phase 1: w [E][K] fp32 -> bf16 (B^T layout already)
__global__ __launch_bounds__(256)
void wconv_kernel(const float* __restrict__ w, unsigned short* __restrict__ Wb)
{
    const unsigned g = blockIdx.x * 256 + threadIdx.x;   // < E_*K_/4
    float4 f = ((const float4*)w)[g];
    uint2 pk;
    pk.x = rnepair(f.x, f.y);
    pk.y = rnepair(f.z, f.w);
    *(uint2*)(Wb + (size_t)g * 4) = pk;
}

// ---------------------------------------------------------------------------
// Fused gather+GEMM, pipelined. All global loads are reg-staged so barriers
// need only lgkmcnt(0) (raw s_barrier, no vmcnt(0) drain); A(t+1)/B(t+1)
// loads stay in flight across both barriers (issue->consume = 1 iteration).
// Both A and B LDS tiles are XOR-swizzled (byte ^ (row&7)<<4) on write AND
// read: without it a [128 rows x 128B] tile is a 16-way read conflict.
// ---------------------------------------------------------------------------
__global__ __launch_bounds__(256, 3)
void fused_gemm(const float* __restrict__ x,
                const int*   __restrict__ ys,
                const int*   __restrict__ xs,
                const unsigned short* __restrict__ Wb,
                const float* __restrict__ bias,
                float*       __restrict__ out)
{
    __shared__ __align__(16) unsigned short Asm[BM * BK];   // 16 KB
    __shared__ __align__(16) unsigned short Bsm[BN * BK];   // 16 KB

    const int t    = threadIdx.x;
    const int wave = t >> 6;
    const int lane = t & 63;

    // XCD-aware swizzle: 1728 blocks = 8 xcd-groups x 36 m-tiles x 6 e-tiles.
    const int b   = blockIdx.x;
    const int xcd = b & 7;
    const int idx = b >> 3;              // 0..215
    const int mt  = xcd * 36 + idx / 6;  // m-tile 0..287
    const int et  = idx % 6;
    const int m0  = mt * BM;
    const int e0  = et * BN;

    // ---- A gather role: thread -> (patch p = t>>1, half h = t&1) ----
    const int p  = t >> 1;
    const int h  = t & 1;
    const int gp = m0 + p;
    const int bimg = gp / N_;
    const float* xrow = x + (size_t)bimg * CHW_ + ys[gp] * W_ + xs[gp] + 2 * h * W_;
    char* aw = (char*)Asm + p * 128;
    const int awz = (p & 7) << 4;
    const int h64 = h * 64;

    // ---- B staging role (reg-staged, swizzled ds_write) ----
    const int r8 = lane >> 3;                         // 0..7
    const unsigned short* Bg = Wb + (size_t)(e0 + wave * 32 + r8) * K_ + (lane & 7) * 8;
    char* bw = (char*)Bsm + (wave * 32 + r8) * 128 + (((lane & 7) * 16) ^ (r8 << 4));

    // ---- compute role ----
    const int wr   = (wave >> 1) * 64;
    const int wc   = (wave & 1) * 64;
    const int lm   = lane & 15;
    const int quad = lane >> 4;
    const char* Ard = (const char*)Asm + (wr + lm) * 128;
    const char* Brd = (const char*)Bsm + (wc + lm) * 128;
    const int rswz = (lm & 7) << 4;      // row&7 == lm&7 for all fragment rows

    f32x4 acc[4][4];
#pragma unroll
    for (int i = 0; i < 4; ++i)
#pragma unroll
        for (int j = 0; j < 4; ++j)
            acc[i][j] = (f32x4){0.f, 0.f, 0.f, 0.f};

    // prologue: issue A(0) then B(0) (A older in vmcnt order)
    float4 fr[8];
#pragma unroll
    for (int m = 0; m < 4; ++m) fr[m]     = ld16u(xrow + 4 * m);
#pragma unroll
    for (int m = 0; m < 4; ++m) fr[4 + m] = ld16u(xrow + W_ + 4 * m);
    uint4 bq[4];
#pragma unroll
    for (int i2 = 0; i2 < 4; ++i2)
        bq[i2] = *(const uint4*)(Bg + (size_t)i2 * 8 * K_);

#pragma unroll 2
    for (int it = 0; it < KITERS; ++it) {
        // issue A(t+1) first; stays in flight across both barriers below
        float4 nfr[8];
        if (it + 1 < KITERS) {
            const int itn = it + 1;
            const float* rp = xrow + (itn >> 2) * HW_ + ((itn & 3) << 2) * W_;
#pragma unroll
            for (int m = 0; m < 4; ++m) nfr[m]     = ld16u(rp + 4 * m);
#pragma unroll
            for (int m = 0; m < 4; ++m) nfr[4 + m] = ld16u(rp + W_ + 4 * m);
        }
        __builtin_amdgcn_sched_barrier(0);   // pin prefetch issue point

        // A(t): pack + swizzled ds_write (compiler waits vmcnt for fr only)
#pragma unroll
        for (int j = 0; j < 4; ++j) {
            uint4 wv;
            wv.x = rnepair(fr[2*j].x,   fr[2*j].y);
            wv.y = rnepair(fr[2*j].z,   fr[2*j].w);
            wv.z = rnepair(fr[2*j+1].x, fr[2*j+1].y);
            wv.w = rnepair(fr[2*j+1].z, fr[2*j+1].w);
            *(uint4*)(aw + ((h64 + j * 16) ^ awz)) = wv;
        }
        // B(t): swizzled ds_write (waits vmcnt for bq, leaves A(t+1) flying)
#pragma unroll
        for (int i2 = 0; i2 < 4; ++i2)
            *(uint4*)(bw + i2 * (8 * 128)) = bq[i2];

        asm volatile("s_waitcnt lgkmcnt(0)" ::: "memory");
        __builtin_amdgcn_s_barrier();        // tile t LDS ready
        __builtin_amdgcn_sched_barrier(0);

        // issue B(t+1); latency hides under MFMA + barrier + next A-pack
        if (it + 1 < KITERS) {
            const unsigned short* bgn = Bg + (it + 1) * BK;
#pragma unroll
            for (int i2 = 0; i2 < 4; ++i2)
                bq[i2] = *(const uint4*)(bgn + (size_t)i2 * 8 * K_);
        }
        __builtin_amdgcn_sched_barrier(0);

        // MFMA over tile t (swizzled, conflict-free reads)
#pragma unroll
        for (int s = 0; s < 2; ++s) {
            short8 af[4], bfr[4];
#pragma unroll
            for (int i = 0; i < 4; ++i)
                af[i]  = *(const short8*)(Ard + i * (16 * 128)
                                              + ((s * 64 + quad * 16) ^ rswz));
#pragma unroll
            for (int j = 0; j < 4; ++j)
                bfr[j] = *(const short8*)(Brd + j * (16 * 128)
                                              + ((s * 64 + quad * 16) ^ rswz));
#pragma unroll
            for (int i = 0; i < 4; ++i)
#pragma unroll
                for (int j = 0; j < 4; ++j)
                    acc[i][j] = __builtin_amdgcn_mfma_f32_16x16x32_bf16(af[i], bfr[j], acc[i][j], 0, 0, 0);
        }

        asm volatile("" ::: "memory");
        __builtin_amdgcn_s_barrier();        // reads done before next writes
        __builtin_amdgcn_sched_barrier(0);

        if (it + 1 < KITERS) {
#pragma unroll
            for (int m = 0; m < 8; ++m) fr[m] = nfr[m];
        }
    }

    // epilogue: C/D layout col=lane&15, row=quad*4+reg (m89-verified)
    float bv[4];
#pragma unroll
    for (int j = 0; j < 4; ++j) bv[j] = bias[e0 + wc + j * 16 + lm];

#pragma unroll
    for (int i = 0; i < 4; ++i) {
#pragma unroll
        for (int j = 0; j < 4; ++j) {
            const int eo = e0 + wc + j * 16 + lm;
#pragma unroll
            for (int r = 0; r < 4; ++r) {
                const int mo = m0 + wr + i * 16 + quad * 4 + r;
                out[(size_t)mo * E_ + eo] = acc[i][j][r] + bv[j];
            }
        }
    }
}

__global__ void pos_kernel(const int* __restrict__ ys, const int* __restrict__ xs,
                           float* __restrict__ outp)
{
    int i = blockIdx.x * blockDim.x + threadIdx.x;
    if (i < M_) {
        outp[2 * i]     = (float)ys[i];
        outp[2 * i + 1] = (float)xs[i];
    }
}

extern "C" void kernel_launch(void* const* d_in, const int* in_sizes, int n_in,
                              void* d_out, int out_size, void* d_ws, size_t ws_size,
                              hipStream_t stream)
{
    const float* x    = (const float*)d_in[0];
    const int*   ys   = (const int*)d_in[1];
    const int*   xs   = (const int*)d_in[2];
    const float* w    = (const float*)d_in[3];
    const float* bias = (const float*)d_in[4];
    float* out = (float*)d_out;

    unsigned short* Wb = (unsigned short*)d_ws;

    wconv_kernel<<<(E_ * K_ / 4) / 256, 256, 0, stream>>>(w, Wb);

    fused_gemm<<<(M_ / BM) * (E_ / BN), 256, 0, stream>>>(x, ys, xs, Wb, bias, out);

    float* outp = out + (size_t)M_ * E_;
    pos_kernel<<<(M_ + 255) / 256, 256, 0, stream>>>(ys, xs, outp);
}

// Round 4
// 338.329 us; speedup vs baseline: 1.4129x; 1.4129x over previous
//
#include <hip/hip_runtime.h>

// Problem constants
#define B_    64
#define C_    3
#define H_    384
#define W_    384
#define P_    16
#define E_    768
#define N_    576                 // patches per image
#define M_    (B_ * N_)           // 36864 total patches
#define K_    (C_ * P_ * P_)      // 768 reduction dim
#define HW_   (H_ * W_)
#define CHW_  (C_ * H_ * W_)

// GEMM tiling
#define BM    128
#define BN    128
#define BK    64
#define KITERS (K_ / BK)          // 12
#define TILE_BYTES (BM * BK * 2)  // 16 KB per A/B buffer

typedef __attribute__((ext_vector_type(8))) short  short8;   // bf16x8 MFMA operand
typedef __attribute__((ext_vector_type(4))) float  f32x4;    // MFMA accumulator

// round-to-nearest-even f32 pair -> packed bf16x2 (low = a). Bit-identical to
// the original gather's f2bf.
__device__ __forceinline__ unsigned int rnepair(float a, float b) {
    unsigned ua = __float_as_uint(a), ub = __float_as_uint(b);
    ua += 0x7FFFu + ((ua >> 16) & 1u);
    ub += 0x7FFFu + ((ub >> 16) & 1u);
    return (ua >> 16) | (ub & 0xFFFF0000u);
}

// 16B load with only 4B alignment guaranteed (xs is arbitrary).
__device__ __forceinline__ float4 ld16u(const float* p) {
    float4 v;
    __builtin_memcpy(&v, p, 16);
    return v;
}

// Phase 1: w [E][K] fp32 -> bf16 (B^T layout already)
__global__ __launch_bounds__(256)
void wconv_kernel(const float* __restrict__ w, unsigned short* __restrict__ Wb)
{
    const unsigned g = blockIdx.x * 256 + threadIdx.x;   // < E_*K_/4
    float4 f = ((const float4*)w)[g];
    uint2 pk;
    pk.x = rnepair(f.x, f.y);
    pk.y = rnepair(f.z, f.w);
    *(uint2*)(Wb + (size_t)g * 4) = pk;
}

// ---------------------------------------------------------------------------
// Fused gather+GEMM, LDS double-buffered, ONE barrier per K-iter, no vmcnt
// drain in the loop. Per iter: pack regs -> LDS[cur]; issue next-tile global
// loads into the SAME registers (WAR, no copy -> no scratch demotion, the
// round-3 failure); lgkmcnt(0)+s_barrier; MFMA from LDS[cur]. Next-tile loads
// stay in flight across barrier+MFMA (~issue->consume = 1 full iteration).
// Buffer parity replaces the second barrier: writes to [cur] at t+2 happen
// after barrier(t+1), by which point every wave's reads of [cur] at t have
// drained (its own lgkmcnt(0) before barrier(t+1)).
// Both LDS tiles XOR-swizzled (byte ^ (row&7)<<4) on write AND read
// (HW-verified round 3: SQ_LDS_BANK_CONFLICT = 0, refcheck passed).
// ---------------------------------------------------------------------------
__global__ __launch_bounds__(256)
void fused_gemm(const float* __restrict__ x,
                const int*   __restrict__ ys,
                const int*   __restrict__ xs,
                const unsigned short* __restrict__ Wb,
                const float* __restrict__ bias,
                float*       __restrict__ out)
{
    __shared__ __align__(16) unsigned short Asm[2][BM * BK];   // 2 x 16 KB
    __shared__ __align__(16) unsigned short Bsm[2][BN * BK];   // 2 x 16 KB

    const int t    = threadIdx.x;
    const int wave = t >> 6;
    const int lane = t & 63;

    // XCD-aware swizzle: 1728 blocks = 8 xcd-groups x 36 m-tiles x 6 e-tiles.
    // Each XCD owns a disjoint m-range -> x is read ~once from HBM.
    const int b   = blockIdx.x;
    const int xcd = b & 7;
    const int idx = b >> 3;              // 0..215
    const int mt  = xcd * 36 + idx / 6;  // m-tile 0..287
    const int et  = idx % 6;
    const int m0  = mt * BM;
    const int e0  = et * BN;

    // ---- A gather role: thread -> (patch p = t>>1, half h = t&1) ----
    const int p  = t >> 1;
    const int h  = t & 1;
    const int gp = m0 + p;
    const int bimg = gp / N_;
    const float* xrow = x + (size_t)bimg * CHW_ + ys[gp] * W_ + xs[gp] + 2 * h * W_;
    char* aw = (char*)&Asm[0][0] + p * 128;
    const int awz = (p & 7) << 4;
    const int h64 = h * 64;

    // ---- B staging role (reg-staged, swizzled ds_write) ----
    const int r8 = lane >> 3;                         // 0..7
    const unsigned short* Bg = Wb + (size_t)(e0 + wave * 32 + r8) * K_ + (lane & 7) * 8;
    char* bw = (char*)&Bsm[0][0] + (wave * 32 + r8) * 128 + (((lane & 7) * 16) ^ (r8 << 4));

    // ---- compute role ----
    const int wr   = (wave >> 1) * 64;
    const int wc   = (wave & 1) * 64;
    const int lm   = lane & 15;
    const int quad = lane >> 4;
    const char* Ard = (const char*)&Asm[0][0] + (wr + lm) * 128;
    const char* Brd = (const char*)&Bsm[0][0] + (wc + lm) * 128;
    const int rswz = (lm & 7) << 4;      // row&7 == lm&7 for all fragment rows

    f32x4 acc[4][4];
#pragma unroll
    for (int i = 0; i < 4; ++i)
#pragma unroll
        for (int j = 0; j < 4; ++j)
            acc[i][j] = (f32x4){0.f, 0.f, 0.f, 0.f};

    // prologue: issue tile-0 loads (A then B)
    float4 fr[8];
#pragma unroll
    for (int m = 0; m < 4; ++m) fr[m]     = ld16u(xrow + 4 * m);
#pragma unroll
    for (int m = 0; m < 4; ++m) fr[4 + m] = ld16u(xrow + W_ + 4 * m);
    uint4 bq[4];
#pragma unroll
    for (int i2 = 0; i2 < 4; ++i2)
        bq[i2] = *(const uint4*)(Bg + (size_t)i2 * 8 * K_);

#pragma unroll 2
    for (int it = 0; it < KITERS; ++it) {
        const int cur = it & 1;                      // static after unroll 2

        // pack A(t) + swizzled ds_write into buffer cur
        char* awc = aw + cur * TILE_BYTES;
#pragma unroll
        for (int j = 0; j < 4; ++j) {
            uint4 wv;
            wv.x = rnepair(fr[2*j].x,   fr[2*j].y);
            wv.y = rnepair(fr[2*j].z,   fr[2*j].w);
            wv.z = rnepair(fr[2*j+1].x, fr[2*j+1].y);
            wv.w = rnepair(fr[2*j+1].z, fr[2*j+1].w);
            *(uint4*)(awc + ((h64 + j * 16) ^ awz)) = wv;
        }
        // B(t) swizzled ds_write into buffer cur
        char* bwc = bw + cur * TILE_BYTES;
#pragma unroll
        for (int i2 = 0; i2 < 4; ++i2)
            *(uint4*)(bwc + i2 * (8 * 128)) = bq[i2];

        // issue tile t+1 loads into the SAME regs (WAR after the ds_writes
        // consumed them) — in flight across barrier + MFMA below
        if (it + 1 < KITERS) {
            const int itn = it + 1;
            const float* rp = xrow + (itn >> 2) * HW_ + ((itn & 3) << 2) * W_;
#pragma unroll
            for (int m = 0; m < 4; ++m) fr[m]     = ld16u(rp + 4 * m);
#pragma unroll
            for (int m = 0; m < 4; ++m) fr[4 + m] = ld16u(rp + W_ + 4 * m);
            const unsigned short* bgn = Bg + itn * BK;
#pragma unroll
            for (int i2 = 0; i2 < 4; ++i2)
                bq[i2] = *(const uint4*)(bgn + (size_t)i2 * 8 * K_);
        }

        asm volatile("s_waitcnt lgkmcnt(0)" ::: "memory");
        __builtin_amdgcn_sched_barrier(0);           // rule-18 fence
        __builtin_amdgcn_s_barrier();                // tile t LDS ready

        // MFMA over tile t (swizzled, conflict-free reads)
        const char* Ac = Ard + cur * TILE_BYTES;
        const char* Bc = Brd + cur * TILE_BYTES;
#pragma unroll
        for (int s = 0; s < 2; ++s) {
            short8 af[4], bfr[4];
#pragma unroll
            for (int i = 0; i < 4; ++i)
                af[i]  = *(const short8*)(Ac + i * (16 * 128)
                                             + ((s * 64 + quad * 16) ^ rswz));
#pragma unroll
            for (int j = 0; j < 4; ++j)
                bfr[j] = *(const short8*)(Bc + j * (16 * 128)
                                             + ((s * 64 + quad * 16) ^ rswz));
#pragma unroll
            for (int i = 0; i < 4; ++i)
#pragma unroll
                for (int j = 0; j < 4; ++j)
                    acc[i][j] = __builtin_amdgcn_mfma_f32_16x16x32_bf16(af[i], bfr[j], acc[i][j], 0, 0, 0);
        }
    }

    // epilogue: C/D layout col=lane&15, row=quad*4+reg (m89-verified)
    float bv[4];
#pragma unroll
    for (int j = 0; j < 4; ++j) bv[j] = bias[e0 + wc + j * 16 + lm];

#pragma unroll
    for (int i = 0; i < 4; ++i) {
#pragma unroll
        for (int j = 0; j < 4; ++j) {
            const int eo = e0 + wc + j * 16 + lm;
#pragma unroll
            for (int r = 0; r < 4; ++r) {
                const int mo = m0 + wr + i * 16 + quad * 4 + r;
                out[(size_t)mo * E_ + eo] = acc[i][j][r] + bv[j];
            }
        }
    }
}

__global__ void pos_kernel(const int* __restrict__ ys, const int* __restrict__ xs,
                           float* __restrict__ outp)
{
    int i = blockIdx.x * blockDim.x + threadIdx.x;
    if (i < M_) {
        outp[2 * i]     = (float)ys[i];
        outp[2 * i + 1] = (float)xs[i];
    }
}

extern "C" void kernel_launch(void* const* d_in, const int* in_sizes, int n_in,
                              void* d_out, int out_size, void* d_ws, size_t ws_size,
                              hipStream_t stream)
{
    const float* x    = (const float*)d_in[0];
    const int*   ys   = (const int*)d_in[1];
    const int*   xs   = (const int*)d_in[2];
    const float* w    = (const float*)d_in[3];
    const float* bias = (const float*)d_in[4];
    float* out = (float*)d_out;

    unsigned short* Wb = (unsigned short*)d_ws;

    wconv_kernel<<<(E_ * K_ / 4) / 256, 256, 0, stream>>>(w, Wb);

    fused_gemm<<<(M_ / BM) * (E_ / BN), 256, 0, stream>>>(x, ys, xs, Wb, bias, out);

    float* outp = out + (size_t)M_ * E_;
    pos_kernel<<<(M_ + 255) / 256, 256, 0, stream>>>(ys, xs, outp);
}